// Round 5
// baseline (446.412 us; speedup 1.0000x reference)
//
#include <hip/hip_runtime.h>
#include <hip/hip_bf16.h>

// KeySelect2 round 10: arithmetic-intensity round. r0/r1/r3 (three sync
// structures) all pinned at MfmaUtil ~25%; r4 proved more waves/SIMD doesn't
// help (ragged 3/CU regressed). The cap is the per-tap MFMA:overhead duty
// cycle: 16 MFMA vs 4 A-loads + 4 ds_reads. This round doubles the duty
// cycle: wave tile 128oc x 64pix (acc[8][4] = 128 AGPR), 32 MFMA per tap
// against the SAME 4 ds_reads; A loaded global->reg in two 4-frag half
// clusters with fixed-role X/Y ping-pong (A reg cost unchanged). Block =
// 128oc x 256pix (4 rows), x slab 6 slots x 2 buffers = 48 KB LDS. Grid
// conv1/4 = (64, 8) = 512 blocks = exactly 2/CU (no raggedness). Also:
// bnstats_s2 + pool merged into one two-pass kernel (pass 2 L2-hot).

#define B_ 4
#define CM_ 128

typedef __attribute__((ext_vector_type(8))) short short8;
typedef __attribute__((ext_vector_type(4))) float floatx4;
typedef __attribute__((address_space(3))) unsigned lds_as;
typedef __attribute__((address_space(1))) const unsigned glb_as;

__device__ inline short f2bf(float f) {
  union { float f; unsigned u; } v; v.f = f;
  unsigned r = v.u + 0x7fff + ((v.u >> 16) & 1);  // RNE
  return (short)(r >> 16);
}
__device__ inline float bf2f(unsigned short u) {
  union { unsigned u; float f; } v; v.u = ((unsigned)u) << 16;
  return v.f;
}

__device__ __forceinline__ void kb_tail() {
  asm volatile("s_waitcnt vmcnt(0)" ::: "memory");
  __builtin_amdgcn_s_barrier();
  asm volatile("" ::: "memory");  // keep subsequent LDS reads below the barrier
}

// ---- x prepack: NCHW fp32 -> [b][kb][row][col][unit^sw][8] bf16 ------------
template <int KB>
__global__ void xprep_kernel(const float* __restrict__ x, short* __restrict__ xt) {
  int kb = blockIdx.x >> 4, rg = blockIdx.x & 15;
  int b = blockIdx.y;
  int row = rg * 4 + (threadIdx.x >> 6);
  int col = threadIdx.x & 63;
  const float* xs = x + (((size_t)b * (KB * 32) + kb * 32) * 64 + row) * 64 + col;
  short* xd = xt + ((((size_t)b * KB + kb) * 64 + row) * 64 + col) * 32;
  int sw = (col >> 1) & 3;
#pragma unroll
  for (int u = 0; u < 4; u++) {
    short8 pk;
#pragma unroll
    for (int j = 0; j < 8; j++) pk[j] = f2bf(xs[(size_t)(u * 8 + j) * 4096]);
    *(short8*)(xd + (u ^ sw) * 8) = pk;
  }
}

// ---- fused prep: xprep(low_key), wfrag 1/4/5, att transpose, zero y1+y4 ----
__global__ void prep1_kernel(const float* __restrict__ x1,
                             const float* __restrict__ w1, const float* __restrict__ w4,
                             const float* __restrict__ w5, const float* __restrict__ atten,
                             short* __restrict__ xt, short* __restrict__ wf1,
                             short* __restrict__ wf4, short* __restrict__ wf5,
                             float* __restrict__ att_t, float* __restrict__ yz) {
  __shared__ float tile[5184];
  int bx = blockIdx.x, tid = threadIdx.x;
  if (bx < 2048) {  // xprep for low_key
    int b = bx & 3, t = bx >> 2;
    int kb = t >> 4, rg = t & 15;
    int row = rg * 4 + (tid >> 6), col = tid & 63;
    const float* xs = x1 + (((size_t)b * 1024 + kb * 32) * 64 + row) * 64 + col;
    short* xd = xt + ((((size_t)b * 32 + kb) * 64 + row) * 64 + col) * 32;
    int sw = (col >> 1) & 3;
#pragma unroll
    for (int u = 0; u < 4; u++) {
      short8 pk;
#pragma unroll
      for (int j = 0; j < 8; j++) pk[j] = f2bf(xs[(size_t)(u * 8 + j) * 4096]);
      *(short8*)(xd + (u ^ sw) * 8) = pk;
    }
    return;
  }
  bx -= 2048;
  if (bx < 1024) {  // wf1 / wf4 (cin=1024)
    const float* w = bx < 512 ? w1 : w4;
    short* wf = bx < 512 ? wf1 : wf4;
    int idx = (bx & 511) * 256 + tid;
    int oc = idx >> 10, ic = idx & 1023;
    int kb = ic >> 5, icb = ic & 31, quad = icb >> 3, j = icb & 7;
    int m = oc >> 4, n16 = oc & 15, lane = quad * 16 + n16;
    const float* wp = w + ((size_t)oc * 1024 + ic) * 9;
    short* base = wf + (size_t)kb * 36864 + lane * 8 + j;
#pragma unroll
    for (int r = 0; r < 3; r++)
#pragma unroll
      for (int s = 0; s < 3; s++)
        base[(size_t)r * 12288 + (s * 8 + m) * 512] = f2bf(wp[r * 3 + s]);
    return;
  }
  bx -= 1024;
  if (bx < 64) {  // wf5 (cin=128)
    int idx = bx * 256 + tid;
    int oc = idx >> 7, ic = idx & 127;
    int kb = ic >> 5, icb = ic & 31, quad = icb >> 3, j = icb & 7;
    int m = oc >> 4, n16 = oc & 15, lane = quad * 16 + n16;
    const float* wp = w5 + ((size_t)oc * 128 + ic) * 9;
    short* base = wf5 + (size_t)kb * 36864 + lane * 8 + j;
#pragma unroll
    for (int r = 0; r < 3; r++)
#pragma unroll
      for (int s = 0; s < 3; s++)
        base[(size_t)r * 12288 + (s * 8 + m) * 512] = f2bf(wp[r * 3 + s]);
    return;
  }
  bx -= 64;
  if (bx < 256) {  // atten [b,pix,81] -> att_t [b,81,pix]
    int b = bx >> 6;
    int p0 = (bx & 63) * 64;
    const float* src = atten + ((size_t)b * 4096 + p0) * 81;
    for (int e = tid; e < 5184; e += 256) tile[e] = src[e];
    __syncthreads();
    for (int f = tid; f < 5184; f += 256) {
      int k = f >> 6, w_ = f & 63;
      att_t[((size_t)b * 81 + k) * 4096 + p0 + w_] = tile[w_ * 81 + k];
    }
    return;
  }
  bx -= 256;
  // zero y1+y4 (16,777,216 B): 4096 blocks x 256 threads x 16 B
  ((float4*)yz)[(size_t)bx * 256 + tid] = make_float4(0.f, 0.f, 0.f, 0.f);
}

// ---- MFMA conv: wave = 128oc x 64pix, A global->reg, x slab in LDS ---------
// grid (64, KSPLIT); block 256 (4 waves). Block tile 128 oc x 256 pix (4 rows,
// wave wv owns row h0+wv). LDS 48 KB: x dbuf, 2 x (6 slots x 2048 shorts).
// Per tap: load A-half Y (4 dwordx4), 4 B ds_read_b128, 16 MFMA (m0-3, X),
// load A-half X for next tap, 16 MFMA (m4-7, Y). One vmcnt(0)+barrier per kb.
template <int KQ, bool ATOMIC>
__global__ __launch_bounds__(256, 2)
void convm_kernel(const short* __restrict__ xt, const short* __restrict__ wf,
                  float* __restrict__ ya, float* __restrict__ yb, int KBtot) {
  __shared__ __attribute__((aligned(16))) short smem[24576];  // 48 KB
  int tid = threadIdx.x, lane = tid & 63, wv = tid >> 6;
  int n16 = lane & 15, quad = lane >> 4;
  int pg = blockIdx.x;
  int b = pg >> 4, h0 = (pg & 15) * 4;
  int kb0 = blockIdx.y * KQ;
  float* yo = ATOMIC ? ya : (blockIdx.y ? yb : ya);

  // pre-zero boundary x slots in BOTH buffers (never DMA'd)
  if (h0 == 0)
    for (int i = tid; i < 1024; i += 256) {
      ((int*)smem)[i] = 0;
      ((int*)(smem + 12288))[i] = 0;
    }
  if (h0 == 60)
    for (int i = tid; i < 1024; i += 256) {
      ((int*)(smem + 5 * 2048))[i] = 0;
      ((int*)(smem + 12288 + 5 * 2048))[i] = 0;
    }

  int xrow1 = h0 - 1 + wv;       // wave wv stages slot wv
  int xrow2 = h0 + 3 + wv;       // waves 0,1 also stage slots 4,5
  int xw1 = __builtin_amdgcn_readfirstlane((xrow1 >= 0 && xrow1 < 64) ? 1 : 0);
  int xw2 = __builtin_amdgcn_readfirstlane((wv < 2 && xrow2 < 64) ? 1 : 0);

  auto dma_x = [&](int kb, int bufi) {
    if (xw1) {
      const short* xs = xt + ((((size_t)b * KBtot + kb) * 64 + xrow1) * 64) * 32 + lane * 8;
      short* xd = smem + bufi * 12288 + wv * 2048 + lane * 8;
#pragma unroll
      for (int t = 0; t < 4; t++)
        __builtin_amdgcn_global_load_lds((glb_as*)(xs + t * 512), (lds_as*)(xd + t * 512),
                                         16, 0, 0);
    }
    if (xw2) {
      const short* xs = xt + ((((size_t)b * KBtot + kb) * 64 + xrow2) * 64) * 32 + lane * 8;
      short* xd = smem + bufi * 12288 + (4 + wv) * 2048 + lane * 8;
#pragma unroll
      for (int t = 0; t < 4; t++)
        __builtin_amdgcn_global_load_lds((glb_as*)(xs + t * 512), (lds_as*)(xd + t * 512),
                                         16, 0, 0);
    }
  };

  // A-fragment base: frag (step, m) at wfa + step*4096 + m*512  (m = 0..7)
  const short* wfa = wf + (size_t)kb0 * 36864 + lane * 8;

  // loop-invariant B-read offsets (shorts) + boundary-zero masks
  int boff[3][4];
#pragma unroll
  for (int sp = 0; sp < 3; sp++)
#pragma unroll
    for (int n = 0; n < 4; n++) {
      int c = n * 16 + n16 + sp - 1;
      int cc = c < 0 ? 0 : (c > 63 ? 63 : c);
      boff[sp][n] = cc * 32 + (quad ^ ((cc >> 1) & 3)) * 8;
    }
  bool bz00 = (n16 == 0), bz32 = (n16 == 15);

  floatx4 acc[8][4];
#pragma unroll
  for (int i = 0; i < 8; i++)
#pragma unroll
    for (int n = 0; n < 4; n++) acc[i][n] = (floatx4){0.f, 0.f, 0.f, 0.f};

  short8 AX[4], AY[4];

  // ---- prologue: x(kb0) -> buf0; A(step 0, m0-3) -> AX ----
  dma_x(kb0, 0);
#pragma unroll
  for (int j = 0; j < 4; j++) AX[j] = *(const short8*)(wfa + j * 512);
  asm volatile("s_waitcnt lgkmcnt(0)" ::: "memory");  // boundary zeroes visible
  kb_tail();  // full drain + barrier: buf0 + AX ready for everyone

// TAP: consume AX (m0-3) and AY (m4-7) for tap E of kb q; AY loaded at tap
// start, AX for next step loaded between the two MFMA clusters.
#define TAP(E, DOXV, SKIP2)                                                          \
  {                                                                                  \
    constexpr int rr_ = (E) / 3, sp_ = (E) % 3;                                      \
    const short* ap_ = wfa + (size_t)(9 * q + (E)) * 4096;                           \
    _Pragma("unroll")                                                                \
    for (int j = 0; j < 4; j++) AY[j] = *(const short8*)(ap_ + (4 + j) * 512);       \
    if (DOXV) dma_x(kb0 + q + 1, bufc ^ 1);                                          \
    const short* sxr_ = smem + bufc * 12288 + (wv + rr_) * 2048;                     \
    short8 bf_[4];                                                                   \
    _Pragma("unroll")                                                                \
    for (int n = 0; n < 4; n++) {                                                    \
      short8 bv = *(const short8*)(sxr_ + boff[sp_][n]);                             \
      if ((n == 0 && sp_ == 0) || (n == 3 && sp_ == 2)) {                            \
        short8 zz = {0, 0, 0, 0, 0, 0, 0, 0};                                        \
        bv = ((sp_ == 0) ? bz00 : bz32) ? zz : bv;                                   \
      }                                                                              \
      bf_[n] = bv;                                                                   \
    }                                                                                \
    __builtin_amdgcn_s_setprio(1);                                                   \
    _Pragma("unroll")                                                                \
    for (int n = 0; n < 4; n++)                                                      \
      _Pragma("unroll")                                                              \
      for (int j = 0; j < 4; j++)                                                    \
        acc[j][n] =                                                                  \
            __builtin_amdgcn_mfma_f32_16x16x32_bf16(AX[j], bf_[n], acc[j][n], 0, 0, 0); \
    __builtin_amdgcn_s_setprio(0);                                                   \
    if (!(SKIP2)) {                                                                  \
      const short* an_ = wfa + (size_t)(9 * q + (E) + 1) * 4096;                     \
      _Pragma("unroll")                                                              \
      for (int j = 0; j < 4; j++) AX[j] = *(const short8*)(an_ + j * 512);           \
    }                                                                                \
    __builtin_amdgcn_s_setprio(1);                                                   \
    _Pragma("unroll")                                                                \
    for (int n = 0; n < 4; n++)                                                      \
      _Pragma("unroll")                                                              \
      for (int j = 0; j < 4; j++)                                                    \
        acc[4 + j][n] =                                                              \
            __builtin_amdgcn_mfma_f32_16x16x32_bf16(AY[j], bf_[n], acc[4 + j][n], 0, 0, 0); \
    __builtin_amdgcn_s_setprio(0);                                                   \
  }

  for (int q = 0; q < KQ; ++q) {
    int bufc = q & 1;
    bool lastq = (q == KQ - 1);
    bool dox0 = !lastq;
    TAP(0, dox0, false)
    TAP(1, false, false)
    TAP(2, false, false)
    TAP(3, false, false)
    TAP(4, false, false)
    TAP(5, false, false)
    TAP(6, false, false)
    TAP(7, false, false)
    TAP(8, false, lastq)
    if (!lastq) kb_tail();
  }
#undef TAP

  int orow = h0 + wv;
#pragma unroll
  for (int i = 0; i < 8; i++)
#pragma unroll
    for (int n = 0; n < 4; n++)
#pragma unroll
      for (int rg = 0; rg < 4; rg++) {
        int oc = i * 16 + quad * 4 + rg;  // D: row=quad*4+reg, col=n16
        size_t gi = (((size_t)b * CM_ + oc) * 64 + orow) * 64 + n * 16 + n16;
        if (ATOMIC)
          atomicAdd(&yo[gi], acc[i][n][rg]);
        else
          yo[gi] = acc[i][n][rg];
      }
}

// ---- BN stats (pair: by=0 -> set1, by=1 -> set4) ---------------------------
__global__ void bnstats2_kernel(const float* __restrict__ y1, const float* __restrict__ g1,
                                const float* __restrict__ b1, float2* __restrict__ s1,
                                const float* __restrict__ y4, const float* __restrict__ g4,
                                const float* __restrict__ b4, float2* __restrict__ s4) {
  const float* y = blockIdx.y ? y4 : y1;
  const float* g = blockIdx.y ? g4 : g1;
  const float* bt = blockIdx.y ? b4 : b1;
  float2* scsh = blockIdx.y ? s4 : s1;
  int c = blockIdx.x;
  int tid = threadIdx.x;
  float s = 0.f, s2 = 0.f;
  for (int b = 0; b < B_; b++) {
    const float4* p = (const float4*)(y + ((size_t)(b * CM_) + c) * 4096);
    for (int i = tid; i < 1024; i += 256) {
      float4 v = p[i];
      s += v.x + v.y + v.z + v.w;
      s2 += v.x * v.x + v.y * v.y + v.z * v.z + v.w * v.w;
    }
  }
  for (int off = 32; off > 0; off >>= 1) {
    s += __shfl_down(s, off);
    s2 += __shfl_down(s2, off);
  }
  __shared__ float rs[4], rq[4];
  if ((tid & 63) == 0) { rs[tid >> 6] = s; rq[tid >> 6] = s2; }
  __syncthreads();
  if (tid == 0) {
    float S = rs[0] + rs[1] + rs[2] + rs[3];
    float Q = rq[0] + rq[1] + rq[2] + rq[3];
    float mean = S * (1.f / 16384.f);
    float var = Q * (1.f / 16384.f) - mean * mean;
    float sc = g[c] * rsqrtf(var + 1e-5f);
    scsh[c] = make_float2(sc, bt[c] - mean * sc);
  }
}

// ---- BN stats over y5 = ya+yb, then fused pool (pass 2 is L2-hot) ----------
__global__ void bnpool_kernel(const float* __restrict__ ya, const float* __restrict__ yb,
                              const float* __restrict__ g, const float* __restrict__ bt,
                              float* __restrict__ pooled) {
  int c = blockIdx.x;
  int tid = threadIdx.x;
  float s = 0.f, s2 = 0.f;
  for (int b = 0; b < B_; b++) {
    const float4* p = (const float4*)(ya + ((size_t)(b * CM_) + c) * 4096);
    const float4* q = (const float4*)(yb + ((size_t)(b * CM_) + c) * 4096);
    for (int i = tid; i < 1024; i += 256) {
      float4 v = p[i], w = q[i];
      float a0 = v.x + w.x, a1 = v.y + w.y, a2 = v.z + w.z, a3 = v.w + w.w;
      s += a0 + a1 + a2 + a3;
      s2 += a0 * a0 + a1 * a1 + a2 * a2 + a3 * a3;
    }
  }
  for (int off = 32; off > 0; off >>= 1) {
    s += __shfl_down(s, off);
    s2 += __shfl_down(s2, off);
  }
  __shared__ float rs[4], rq[4];
  __shared__ float2 ss_sh;
  if ((tid & 63) == 0) { rs[tid >> 6] = s; rq[tid >> 6] = s2; }
  __syncthreads();
  if (tid == 0) {
    float S = rs[0] + rs[1] + rs[2] + rs[3];
    float Q = rq[0] + rq[1] + rq[2] + rq[3];
    float mean = S * (1.f / 16384.f);
    float var = Q * (1.f / 16384.f) - mean * mean;
    float sc = g[c] * rsqrtf(var + 1e-5f);
    ss_sh = make_float2(sc, bt[c] - mean * sc);
  }
  __syncthreads();
  float2 ss = ss_sh;
  float pb[B_];
#pragma unroll
  for (int b = 0; b < B_; b++) pb[b] = 0.f;
  for (int b = 0; b < B_; b++) {
    const float4* p = (const float4*)(ya + ((size_t)(b * CM_) + c) * 4096);
    const float4* q = (const float4*)(yb + ((size_t)(b * CM_) + c) * 4096);
    for (int i = tid; i < 1024; i += 256) {
      float4 v = p[i], w = q[i];
      pb[b] += fmaxf(0.f, (v.x + w.x) * ss.x + ss.y) + fmaxf(0.f, (v.y + w.y) * ss.x + ss.y) +
               fmaxf(0.f, (v.z + w.z) * ss.x + ss.y) + fmaxf(0.f, (v.w + w.w) * ss.x + ss.y);
    }
  }
  for (int off = 32; off > 0; off >>= 1)
#pragma unroll
    for (int b = 0; b < B_; b++) pb[b] += __shfl_down(pb[b], off);
  __shared__ float pbs[4][B_];
  if ((tid & 63) == 0)
#pragma unroll
    for (int b = 0; b < B_; b++) pbs[tid >> 6][b] = pb[b];
  __syncthreads();
  if (tid < B_)
    pooled[tid * CM_ + c] =
        (pbs[0][tid] + pbs[1][tid] + pbs[2][tid] + pbs[3][tid]) * (1.f / 4096.f);
}

// ---- local weighting + subtract -> xt5 (bf16, conv5 layout) ----------------
__global__ __launch_bounds__(256, 2)
void localw_kernel(const float* __restrict__ y1, const float2* __restrict__ scsh1,
                   const float* __restrict__ y4, const float2* __restrict__ scsh4,
                   const float* __restrict__ att_t, short* __restrict__ xt5) {
  __shared__ unsigned short lkb[16][12][72];
  int bx = blockIdx.x;
  int b = bx >> 4, h0 = (bx & 15) * 4;
  int cg = blockIdx.y;
  int tid = threadIdx.x;
  int lane = tid & 63;
  int wv = tid >> 6;

  for (int e = tid; e < 16 * 12 * 72; e += 256) {
    int c_l = e / (12 * 72);
    int rem = e % (12 * 72);
    int gri = rem / 72, j = rem % 72;
    int row = h0 - 4 + gri, col = j - 4;
    float v = 0.f;
    if (row >= 0 && row < 64 && col >= 0 && col < 64) {
      float2 ss = scsh1[cg * 16 + c_l];
      v = fmaxf(0.f, y1[((size_t)(b * CM_) + cg * 16 + c_l) * 4096 + row * 64 + col] * ss.x + ss.y);
    }
    lkb[c_l][gri][j] = (unsigned short)f2bf(v);
  }
  __syncthreads();

  float acc[4][4];
#pragma unroll
  for (int cc = 0; cc < 4; cc++)
#pragma unroll
    for (int h_i = 0; h_i < 4; h_i++) acc[cc][h_i] = 0.f;

  const float* ab = att_t + (size_t)b * 81 * 4096 + h0 * 64 + lane;

#pragma unroll
  for (int gri = 0; gri < 12; ++gri) {
    float win[4][9];
#pragma unroll
    for (int cc = 0; cc < 4; ++cc)
#pragma unroll
      for (int dw = 0; dw < 9; ++dw)
        win[cc][dw] = bf2f(lkb[wv * 4 + cc][gri][lane + dw]);
#pragma unroll
    for (int h_i = 0; h_i < 4; ++h_i) {
      int r = gri - h_i;
      if (r < 0 || r > 8) continue;
      const float* ap = ab + (size_t)(r * 9) * 4096 + h_i * 64;
      float a[9];
#pragma unroll
      for (int dw = 0; dw < 9; ++dw) a[dw] = ap[(size_t)dw * 4096];
#pragma unroll
      for (int cc = 0; cc < 4; ++cc)
#pragma unroll
        for (int dw = 0; dw < 9; ++dw)
          acc[cc][h_i] = fmaf(a[dw], win[cc][dw], acc[cc][h_i]);
    }
  }

#pragma unroll
  for (int cc = 0; cc < 4; ++cc) {
    int c = cg * 16 + wv * 4 + cc;
    float2 ss4 = scsh4[c];
    int icb = c & 31;
    int uu = (icb >> 3) ^ ((lane >> 1) & 3);
#pragma unroll
    for (int h_i = 0; h_i < 4; ++h_i) {
      int h = h0 + h_i;
      size_t gi = ((size_t)(b * CM_) + c) * 4096 + h * 64 + lane;
      float lnk = fmaxf(0.f, y4[gi] * ss4.x + ss4.y);
      float dv = acc[cc][h_i] - lnk;
      xt5[((((size_t)b * 4 + (c >> 5)) * 64 + h) * 64 + lane) * 32 + uu * 8 + (icb & 7)] =
          f2bf(dv);
    }
  }
}

// ---- fc1 + fc2 -------------------------------------------------------------
__global__ void fc_kernel(const float* __restrict__ pooled, const float* __restrict__ fc1w,
                          const float* __restrict__ fc1b, const float* __restrict__ fc2w,
                          const float* __restrict__ fc2b, float* __restrict__ out) {
  int lane = threadIdx.x;
  float p[B_][10];
#pragma unroll
  for (int b = 0; b < B_; b++)
#pragma unroll
    for (int j = 0; j < 10; j++) p[b][j] = 0.f;
  for (int c = lane; c < CM_; c += 64) {
#pragma unroll
    for (int b = 0; b < B_; b++) {
      float pv = pooled[b * CM_ + c];
#pragma unroll
      for (int j = 0; j < 10; j++) p[b][j] = fmaf(pv, fc1w[j * CM_ + c], p[b][j]);
    }
  }
  for (int off = 32; off > 0; off >>= 1)
#pragma unroll
    for (int b = 0; b < B_; b++)
#pragma unroll
      for (int j = 0; j < 10; j++) p[b][j] += __shfl_down(p[b][j], off);
  if (lane == 0) {
    for (int b = 0; b < B_; b++) {
      float o = fc2b[0];
      for (int j = 0; j < 10; j++) o += fc2w[j] * (p[b][j] + fc1b[j]);
      out[b] = o;
    }
  }
}

extern "C" void kernel_launch(void* const* d_in, const int* in_sizes, int n_in,
                              void* d_out, int out_size, void* d_ws, size_t ws_size,
                              hipStream_t stream) {
  const float* low_key    = (const float*)d_in[0];
  const float* low_nonkey = (const float*)d_in[1];
  const float* atten      = (const float*)d_in[2];
  const float* w1  = (const float*)d_in[3];
  const float* g1  = (const float*)d_in[4];
  const float* b1  = (const float*)d_in[5];
  const float* w4  = (const float*)d_in[6];
  const float* g4  = (const float*)d_in[7];
  const float* b4  = (const float*)d_in[8];
  const float* w5  = (const float*)d_in[9];
  const float* g5  = (const float*)d_in[10];
  const float* b5  = (const float*)d_in[11];
  const float* fc1w = (const float*)d_in[12];
  const float* fc1b = (const float*)d_in[13];
  const float* fc2w = (const float*)d_in[14];
  const float* fc2b = (const float*)d_in[15];

  char* w8 = (char*)d_ws;
  short* wf1   = (short*)w8;                       // 2,359,296 B
  short* wf4   = (short*)(w8 + 2359296);           // 2,359,296 B
  short* wf5   = (short*)(w8 + 4718592);           //   294,912 B (pad to 589,824)
  float* att_t = (float*)(w8 + 5308416);           // 5,308,416 B
  short* xt    = (short*)(w8 + 10616832);          // 33,554,432 B (xt5 aliases base)
  float* y1    = (float*)(w8 + 44171264);          // 8,388,608 B (zeroed; conv1 acc; y5a)
  float* y4    = (float*)(w8 + 52559872);          // 8,388,608 B (zeroed; conv4 acc; y5b)
  float2* scsh1 = (float2*)(w8 + 60948480);
  float2* scsh4 = scsh1 + CM_;
  float2* scsh5 = scsh4 + CM_;
  float* pooled = (float*)(scsh5 + CM_);
  short* xt5 = xt;  // conv5 input, written by localw after xt is dead
  float* out = (float*)d_out;

  // 1. fused prep: xt(low_key), wf1/wf4/wf5 fragment-major, att_t, zero y1+y4
  prep1_kernel<<<7488, 256, 0, stream>>>(low_key, w1, w4, w5, atten,
                                         xt, wf1, wf4, wf5, att_t, y1);
  // 2. conv1: K-split x8, grid 512 = exactly 2 blocks/CU, atomic into y1
  convm_kernel<4, true><<<dim3(64, 8), 256, 0, stream>>>(xt, wf1, y1, y1, 32);
  // 3. xprep for low_nonkey (reuses xt)
  xprep_kernel<32><<<dim3(512, 4), 256, 0, stream>>>(low_nonkey, xt);
  // 4. conv4
  convm_kernel<4, true><<<dim3(64, 8), 256, 0, stream>>>(xt, wf4, y4, y4, 32);
  // 5. BN stats for conv1 & conv4 in one launch
  bnstats2_kernel<<<dim3(128, 2), 256, 0, stream>>>(y1, g1, b1, scsh1, y4, g4, b4, scsh4);
  // 6. local weighting + subtract -> xt5 (bf16 conv5 layout)
  localw_kernel<<<dim3(64, 8), 256, 0, stream>>>(y1, scsh1, y4, scsh4, att_t, xt5);
  // 7. conv5: K-split x2, non-atomic partials into now-dead y1/y4 regions
  convm_kernel<2, false><<<dim3(64, 2), 256, 0, stream>>>(xt5, wf5, y1, y4, 4);
  // 8+9. BN stats over y5 = y1+y4 partials, fused with pool (L2-hot 2nd pass)
  bnpool_kernel<<<128, 256, 0, stream>>>(y1, y4, g5, b5, pooled);
  // 10. fc
  fc_kernel<<<1, 64, 0, stream>>>(pooled, fc1w, fc1b, fc2w, fc2b, out);
}

// Round 6
// 401.925 us; speedup vs baseline: 1.1107x; 1.1107x over previous
//
#include <hip/hip_runtime.h>
#include <hip/hip_bf16.h>

// KeySelect2 round 11: clean-occupancy round. Cross-round analysis: r0/r1/r3
// (three sync structures, 8 waves/CU) all show per-wave MFMA duty 12.5% --
// identical to m97's verified GEMM (12.3% at 12 waves/CU). Per-wave pipeline
// is at parity; the whole gap is waves/CU. r4's 3/CU attempt was ragged
// (1024 long blocks = 768 + 256 tail). This round: K-split 6 (uneven 5/5/5/
// 5/6/6, runtime kb loop) -> grid (128,6) = 768 blocks = EXACTLY 3 blocks/CU.
// PH tap pipeline, regs (84+64=148<=170), LDS (32KB*3=96<=160) unchanged from
// the r8-verified kernel. launch_bounds(256,3). r5's 128oc wave tile reverted
// (same-tap A consumption exposed L2/HBM latency; 6000 cyc/tap). bnpool
// fusion (r5, verified) kept.

#define B_ 4
#define CM_ 128

typedef __attribute__((ext_vector_type(8))) short short8;
typedef __attribute__((ext_vector_type(4))) float floatx4;
typedef __attribute__((address_space(3))) unsigned lds_as;
typedef __attribute__((address_space(1))) const unsigned glb_as;

__device__ inline short f2bf(float f) {
  union { float f; unsigned u; } v; v.f = f;
  unsigned r = v.u + 0x7fff + ((v.u >> 16) & 1);  // RNE
  return (short)(r >> 16);
}
__device__ inline float bf2f(unsigned short u) {
  union { unsigned u; float f; } v; v.u = ((unsigned)u) << 16;
  return v.f;
}

__device__ __forceinline__ void kb_tail() {
  asm volatile("s_waitcnt vmcnt(0)" ::: "memory");
  __builtin_amdgcn_s_barrier();
  asm volatile("" ::: "memory");  // keep subsequent LDS reads below the barrier
}

// ---- x prepack: NCHW fp32 -> [b][kb][row][col][unit^sw][8] bf16 ------------
template <int KB>
__global__ void xprep_kernel(const float* __restrict__ x, short* __restrict__ xt) {
  int kb = blockIdx.x >> 4, rg = blockIdx.x & 15;
  int b = blockIdx.y;
  int row = rg * 4 + (threadIdx.x >> 6);
  int col = threadIdx.x & 63;
  const float* xs = x + (((size_t)b * (KB * 32) + kb * 32) * 64 + row) * 64 + col;
  short* xd = xt + ((((size_t)b * KB + kb) * 64 + row) * 64 + col) * 32;
  int sw = (col >> 1) & 3;
#pragma unroll
  for (int u = 0; u < 4; u++) {
    short8 pk;
#pragma unroll
    for (int j = 0; j < 8; j++) pk[j] = f2bf(xs[(size_t)(u * 8 + j) * 4096]);
    *(short8*)(xd + (u ^ sw) * 8) = pk;
  }
}

// ---- fused prep: xprep(low_key), wfrag 1/4/5, att transpose, zero y1+y4 ----
__global__ void prep1_kernel(const float* __restrict__ x1,
                             const float* __restrict__ w1, const float* __restrict__ w4,
                             const float* __restrict__ w5, const float* __restrict__ atten,
                             short* __restrict__ xt, short* __restrict__ wf1,
                             short* __restrict__ wf4, short* __restrict__ wf5,
                             float* __restrict__ att_t, float* __restrict__ yz) {
  __shared__ float tile[5184];
  int bx = blockIdx.x, tid = threadIdx.x;
  if (bx < 2048) {  // xprep for low_key
    int b = bx & 3, t = bx >> 2;
    int kb = t >> 4, rg = t & 15;
    int row = rg * 4 + (tid >> 6), col = tid & 63;
    const float* xs = x1 + (((size_t)b * 1024 + kb * 32) * 64 + row) * 64 + col;
    short* xd = xt + ((((size_t)b * 32 + kb) * 64 + row) * 64 + col) * 32;
    int sw = (col >> 1) & 3;
#pragma unroll
    for (int u = 0; u < 4; u++) {
      short8 pk;
#pragma unroll
      for (int j = 0; j < 8; j++) pk[j] = f2bf(xs[(size_t)(u * 8 + j) * 4096]);
      *(short8*)(xd + (u ^ sw) * 8) = pk;
    }
    return;
  }
  bx -= 2048;
  if (bx < 1024) {  // wf1 / wf4 (cin=1024)
    const float* w = bx < 512 ? w1 : w4;
    short* wf = bx < 512 ? wf1 : wf4;
    int idx = (bx & 511) * 256 + tid;
    int oc = idx >> 10, ic = idx & 1023;
    int kb = ic >> 5, icb = ic & 31, quad = icb >> 3, j = icb & 7;
    int m = oc >> 4, n16 = oc & 15, lane = quad * 16 + n16;
    const float* wp = w + ((size_t)oc * 1024 + ic) * 9;
    short* base = wf + (size_t)kb * 36864 + lane * 8 + j;
#pragma unroll
    for (int r = 0; r < 3; r++)
#pragma unroll
      for (int s = 0; s < 3; s++)
        base[(size_t)r * 12288 + (s * 8 + m) * 512] = f2bf(wp[r * 3 + s]);
    return;
  }
  bx -= 1024;
  if (bx < 64) {  // wf5 (cin=128)
    int idx = bx * 256 + tid;
    int oc = idx >> 7, ic = idx & 127;
    int kb = ic >> 5, icb = ic & 31, quad = icb >> 3, j = icb & 7;
    int m = oc >> 4, n16 = oc & 15, lane = quad * 16 + n16;
    const float* wp = w5 + ((size_t)oc * 128 + ic) * 9;
    short* base = wf5 + (size_t)kb * 36864 + lane * 8 + j;
#pragma unroll
    for (int r = 0; r < 3; r++)
#pragma unroll
      for (int s = 0; s < 3; s++)
        base[(size_t)r * 12288 + (s * 8 + m) * 512] = f2bf(wp[r * 3 + s]);
    return;
  }
  bx -= 64;
  if (bx < 256) {  // atten [b,pix,81] -> att_t [b,81,pix]
    int b = bx >> 6;
    int p0 = (bx & 63) * 64;
    const float* src = atten + ((size_t)b * 4096 + p0) * 81;
    for (int e = tid; e < 5184; e += 256) tile[e] = src[e];
    __syncthreads();
    for (int f = tid; f < 5184; f += 256) {
      int k = f >> 6, w_ = f & 63;
      att_t[((size_t)b * 81 + k) * 4096 + p0 + w_] = tile[w_ * 81 + k];
    }
    return;
  }
  bx -= 256;
  // zero y1+y4 (16,777,216 B): 4096 blocks x 256 threads x 16 B
  ((float4*)yz)[(size_t)bx * 256 + tid] = make_float4(0.f, 0.f, 0.f, 0.f);
}

// ---- MFMA conv: A global->reg pipelined, x slab in LDS ---------------------
// grid (128, NSPLIT); block 256 (4 waves). Block tile 128 oc x 128 pix.
// LDS 32 KB: x double buffer, 2 x (4 slots x 2048 shorts).
// Per tap: 4 A dwordx4 loads (next tap, ping-pong AA/AB), 4 B ds_read_b128,
// 16 MFMA. One vmcnt(0)+barrier per kb. UNEVEN: splits 0-3 own 5 kbs,
// splits 4-5 own 6 (grid y=6 -> 768 blocks = exactly 3 blocks/CU).
template <bool UNEVEN, int KQ, bool ATOMIC>
__global__ __launch_bounds__(256, 3)
void convm_kernel(const short* __restrict__ xt, const short* __restrict__ wf,
                  float* __restrict__ ya, float* __restrict__ yb, int KBtot) {
  __shared__ __attribute__((aligned(16))) short smem[16384];  // 32 KB
  int tid = threadIdx.x, lane = tid & 63, wv = tid >> 6;
  int n16 = lane & 15, quad = lane >> 4;
  int pg = blockIdx.x;
  int b = pg >> 5, h0 = (pg & 31) * 2;
  int yq = blockIdx.y;
  int nq, kb0;
  if (UNEVEN) {
    nq = (yq < 4) ? 5 : 6;
    kb0 = (yq < 4) ? yq * 5 : 20 + (yq - 4) * 6;
  } else {
    nq = KQ;
    kb0 = yq * KQ;
  }
  int mh = wv & 1, nh = wv >> 1;
  float* yo = ATOMIC ? ya : (blockIdx.y ? yb : ya);

  // pre-zero boundary x slots in BOTH buffers (never DMA'd)
  if (h0 == 0)
    for (int i = tid; i < 1024; i += 256) {
      ((int*)smem)[i] = 0;
      ((int*)(smem + 8192))[i] = 0;
    }
  if (h0 == 62)
    for (int i = tid; i < 1024; i += 256) {
      ((int*)(smem + 3 * 2048))[i] = 0;
      ((int*)(smem + 8192 + 3 * 2048))[i] = 0;
    }

  int xrow = h0 - 1 + wv;  // wave wv stages x slot wv
  int xw = __builtin_amdgcn_readfirstlane((xrow >= 0 && xrow < 64) ? 1 : 0);
  // A-fragment base for this wave: wf + kb0*36864 + p*4096 + ((mh*4+i)*64+lane)*8
  const short* wfa = wf + (size_t)kb0 * 36864 + ((mh * 4) * 64 + lane) * 8;

  // loop-invariant B-read offsets (shorts) + boundary-zero masks
  int boff[3][4];
#pragma unroll
  for (int sp = 0; sp < 3; sp++)
#pragma unroll
    for (int n = 0; n < 4; n++) {
      int c = n * 16 + n16 + sp - 1;
      int cc = c < 0 ? 0 : (c > 63 ? 63 : c);
      boff[sp][n] = cc * 32 + (quad ^ ((cc >> 1) & 3)) * 8;
    }
  bool bz00 = (n16 == 0), bz32 = (n16 == 15);

  floatx4 acc[4][4];
#pragma unroll
  for (int i = 0; i < 4; i++)
#pragma unroll
    for (int n = 0; n < 4; n++) acc[i][n] = (floatx4){0.f, 0.f, 0.f, 0.f};

  short8 AA[4], AB[4];

  // ---- prologue: x(kb0) -> buf0; A for phase 0 -> AA ----
  if (xw) {
    const short* xs = xt + ((((size_t)b * KBtot + kb0) * 64 + xrow) * 64) * 32 + lane * 8;
    short* xd = smem + wv * 2048 + lane * 8;
#pragma unroll
    for (int t = 0; t < 4; t++)
      __builtin_amdgcn_global_load_lds((glb_as*)(xs + t * 512), (lds_as*)(xd + t * 512),
                                       16, 0, 0);
  }
#pragma unroll
  for (int i = 0; i < 4; i++) AA[i] = *(const short8*)(wfa + i * 512);
  asm volatile("s_waitcnt lgkmcnt(0)" ::: "memory");  // boundary zeroes visible
  kb_tail();  // full drain + barrier + fence: buf0 + AA ready for everyone

// Phase (QV, E): consume ACUR, load ANXT for phase+1 (if DONP), optionally
// issue x DMA for kb QV+1 into buf XB (if DOX), MFMA, optional kb-end tail.
#define PH(QV, E, ACUR, ANXT, DONP, DOX, XB, DOTAIL)                                 \
  {                                                                                  \
    constexpr int rr_ = (E) / 3, sp_ = (E) % 3;                                      \
    if (DONP) {                                                                      \
      const short* ap_ = wfa + (size_t)(9 * (QV) + (E) + 1) * 4096;                  \
      _Pragma("unroll")                                                              \
      for (int i = 0; i < 4; i++) ANXT[i] = *(const short8*)(ap_ + i * 512);         \
    }                                                                                \
    if ((DOX) && xw) {                                                               \
      const short* xs_ = xt +                                                        \
          ((((size_t)b * KBtot + kb0 + (QV) + 1) * 64 + xrow) * 64) * 32 + lane * 8; \
      short* xd_ = smem + (XB) * 8192 + wv * 2048 + lane * 8;                        \
      _Pragma("unroll")                                                              \
      for (int t = 0; t < 4; t++)                                                    \
        __builtin_amdgcn_global_load_lds((glb_as*)(xs_ + t * 512),                   \
                                         (lds_as*)(xd_ + t * 512), 16, 0, 0);        \
    }                                                                                \
    const short* sxr_ = smem + ((QV) & 1) * 8192 + (nh + rr_) * 2048;                \
    short8 bf_[4];                                                                   \
    _Pragma("unroll")                                                                \
    for (int n = 0; n < 4; n++) {                                                    \
      short8 bv = *(const short8*)(sxr_ + boff[sp_][n]);                             \
      if ((n == 0 && sp_ == 0) || (n == 3 && sp_ == 2)) {                            \
        short8 zz = {0, 0, 0, 0, 0, 0, 0, 0};                                        \
        bv = ((sp_ == 0) ? bz00 : bz32) ? zz : bv;                                   \
      }                                                                              \
      bf_[n] = bv;                                                                   \
    }                                                                                \
    __builtin_amdgcn_s_setprio(1);                                                   \
    _Pragma("unroll")                                                                \
    for (int n = 0; n < 4; n++)                                                      \
      _Pragma("unroll")                                                              \
      for (int i = 0; i < 4; i++)                                                    \
        acc[i][n] =                                                                  \
            __builtin_amdgcn_mfma_f32_16x16x32_bf16(ACUR[i], bf_[n], acc[i][n], 0, 0, 0); \
    __builtin_amdgcn_s_setprio(0);                                                   \
    if (DOTAIL) kb_tail();                                                           \
  }

  // runtime pair loop (kb parity conventions identical to the verified r8 loop:
  // q0 even starts on AA, q1 odd starts on AB; 9 taps flip parity, pair restores)
  int npair = nq >> 1;
  for (int dq = 0; dq < npair; ++dq) {
    int q0 = 2 * dq, q1 = q0 + 1;
    bool l1 = (q1 == nq - 1);
    // kb q0 (even): reads buf0; E=0 issues x for kb q1 -> buf1 (q1 always exists)
    PH(q0, 0, AA, AB, true, true, 1, false)
    PH(q0, 1, AB, AA, true, false, 0, false)
    PH(q0, 2, AA, AB, true, false, 0, false)
    PH(q0, 3, AB, AA, true, false, 0, false)
    PH(q0, 4, AA, AB, true, false, 0, false)
    PH(q0, 5, AB, AA, true, false, 0, false)
    PH(q0, 6, AA, AB, true, false, 0, false)
    PH(q0, 7, AB, AA, true, false, 0, false)
    PH(q0, 8, AA, AB, true, false, 0, true)
    // kb q1 (odd): reads buf1; E=0 issues x for kb q1+1 -> buf0 unless last
    PH(q1, 0, AB, AA, true, !l1, 0, false)
    PH(q1, 1, AA, AB, true, false, 0, false)
    PH(q1, 2, AB, AA, true, false, 0, false)
    PH(q1, 3, AA, AB, true, false, 0, false)
    PH(q1, 4, AB, AA, true, false, 0, false)
    PH(q1, 5, AA, AB, true, false, 0, false)
    PH(q1, 6, AB, AA, true, false, 0, false)
    PH(q1, 7, AA, AB, true, false, 0, false)
    PH(q1, 8, AB, AA, !l1, false, 0, !l1)
  }
  if (nq & 1) {  // trailing odd kb (even index, starts on AA, is last)
    int qt = nq - 1;
    PH(qt, 0, AA, AB, true, false, 0, false)
    PH(qt, 1, AB, AA, true, false, 0, false)
    PH(qt, 2, AA, AB, true, false, 0, false)
    PH(qt, 3, AB, AA, true, false, 0, false)
    PH(qt, 4, AA, AB, true, false, 0, false)
    PH(qt, 5, AB, AA, true, false, 0, false)
    PH(qt, 6, AA, AB, true, false, 0, false)
    PH(qt, 7, AB, AA, true, false, 0, false)
    PH(qt, 8, AA, AB, false, false, 0, false)
  }
#undef PH

  int orow = h0 + nh;
#pragma unroll
  for (int i = 0; i < 4; i++)
#pragma unroll
    for (int n = 0; n < 4; n++)
#pragma unroll
      for (int rg = 0; rg < 4; rg++) {
        int oc = mh * 64 + i * 16 + quad * 4 + rg;  // D: row=quad*4+reg, col=n16
        size_t gi = (((size_t)b * CM_ + oc) * 64 + orow) * 64 + n * 16 + n16;
        if (ATOMIC)
          atomicAdd(&yo[gi], acc[i][n][rg]);
        else
          yo[gi] = acc[i][n][rg];
      }
}

// ---- BN stats (pair: by=0 -> set1, by=1 -> set4) ---------------------------
__global__ void bnstats2_kernel(const float* __restrict__ y1, const float* __restrict__ g1,
                                const float* __restrict__ b1, float2* __restrict__ s1,
                                const float* __restrict__ y4, const float* __restrict__ g4,
                                const float* __restrict__ b4, float2* __restrict__ s4) {
  const float* y = blockIdx.y ? y4 : y1;
  const float* g = blockIdx.y ? g4 : g1;
  const float* bt = blockIdx.y ? b4 : b1;
  float2* scsh = blockIdx.y ? s4 : s1;
  int c = blockIdx.x;
  int tid = threadIdx.x;
  float s = 0.f, s2 = 0.f;
  for (int b = 0; b < B_; b++) {
    const float4* p = (const float4*)(y + ((size_t)(b * CM_) + c) * 4096);
    for (int i = tid; i < 1024; i += 256) {
      float4 v = p[i];
      s += v.x + v.y + v.z + v.w;
      s2 += v.x * v.x + v.y * v.y + v.z * v.z + v.w * v.w;
    }
  }
  for (int off = 32; off > 0; off >>= 1) {
    s += __shfl_down(s, off);
    s2 += __shfl_down(s2, off);
  }
  __shared__ float rs[4], rq[4];
  if ((tid & 63) == 0) { rs[tid >> 6] = s; rq[tid >> 6] = s2; }
  __syncthreads();
  if (tid == 0) {
    float S = rs[0] + rs[1] + rs[2] + rs[3];
    float Q = rq[0] + rq[1] + rq[2] + rq[3];
    float mean = S * (1.f / 16384.f);
    float var = Q * (1.f / 16384.f) - mean * mean;
    float sc = g[c] * rsqrtf(var + 1e-5f);
    scsh[c] = make_float2(sc, bt[c] - mean * sc);
  }
}

// ---- BN stats over y5 = ya+yb, then fused pool (pass 2 is L2-hot) ----------
__global__ void bnpool_kernel(const float* __restrict__ ya, const float* __restrict__ yb,
                              const float* __restrict__ g, const float* __restrict__ bt,
                              float* __restrict__ pooled) {
  int c = blockIdx.x;
  int tid = threadIdx.x;
  float s = 0.f, s2 = 0.f;
  for (int b = 0; b < B_; b++) {
    const float4* p = (const float4*)(ya + ((size_t)(b * CM_) + c) * 4096);
    const float4* q = (const float4*)(yb + ((size_t)(b * CM_) + c) * 4096);
    for (int i = tid; i < 1024; i += 256) {
      float4 v = p[i], w = q[i];
      float a0 = v.x + w.x, a1 = v.y + w.y, a2 = v.z + w.z, a3 = v.w + w.w;
      s += a0 + a1 + a2 + a3;
      s2 += a0 * a0 + a1 * a1 + a2 * a2 + a3 * a3;
    }
  }
  for (int off = 32; off > 0; off >>= 1) {
    s += __shfl_down(s, off);
    s2 += __shfl_down(s2, off);
  }
  __shared__ float rs[4], rq[4];
  __shared__ float2 ss_sh;
  if ((tid & 63) == 0) { rs[tid >> 6] = s; rq[tid >> 6] = s2; }
  __syncthreads();
  if (tid == 0) {
    float S = rs[0] + rs[1] + rs[2] + rs[3];
    float Q = rq[0] + rq[1] + rq[2] + rq[3];
    float mean = S * (1.f / 16384.f);
    float var = Q * (1.f / 16384.f) - mean * mean;
    float sc = g[c] * rsqrtf(var + 1e-5f);
    ss_sh = make_float2(sc, bt[c] - mean * sc);
  }
  __syncthreads();
  float2 ss = ss_sh;
  float pb[B_];
#pragma unroll
  for (int b = 0; b < B_; b++) pb[b] = 0.f;
  for (int b = 0; b < B_; b++) {
    const float4* p = (const float4*)(ya + ((size_t)(b * CM_) + c) * 4096);
    const float4* q = (const float4*)(yb + ((size_t)(b * CM_) + c) * 4096);
    for (int i = tid; i < 1024; i += 256) {
      float4 v = p[i], w = q[i];
      pb[b] += fmaxf(0.f, (v.x + w.x) * ss.x + ss.y) + fmaxf(0.f, (v.y + w.y) * ss.x + ss.y) +
               fmaxf(0.f, (v.z + w.z) * ss.x + ss.y) + fmaxf(0.f, (v.w + w.w) * ss.x + ss.y);
    }
  }
  for (int off = 32; off > 0; off >>= 1)
#pragma unroll
    for (int b = 0; b < B_; b++) pb[b] += __shfl_down(pb[b], off);
  __shared__ float pbs[4][B_];
  if ((tid & 63) == 0)
#pragma unroll
    for (int b = 0; b < B_; b++) pbs[tid >> 6][b] = pb[b];
  __syncthreads();
  if (tid < B_)
    pooled[tid * CM_ + c] =
        (pbs[0][tid] + pbs[1][tid] + pbs[2][tid] + pbs[3][tid]) * (1.f / 4096.f);
}

// ---- local weighting + subtract -> xt5 (bf16, conv5 layout) ----------------
__global__ __launch_bounds__(256, 2)
void localw_kernel(const float* __restrict__ y1, const float2* __restrict__ scsh1,
                   const float* __restrict__ y4, const float2* __restrict__ scsh4,
                   const float* __restrict__ att_t, short* __restrict__ xt5) {
  __shared__ unsigned short lkb[16][12][72];
  int bx = blockIdx.x;
  int b = bx >> 4, h0 = (bx & 15) * 4;
  int cg = blockIdx.y;
  int tid = threadIdx.x;
  int lane = tid & 63;
  int wv = tid >> 6;

  for (int e = tid; e < 16 * 12 * 72; e += 256) {
    int c_l = e / (12 * 72);
    int rem = e % (12 * 72);
    int gri = rem / 72, j = rem % 72;
    int row = h0 - 4 + gri, col = j - 4;
    float v = 0.f;
    if (row >= 0 && row < 64 && col >= 0 && col < 64) {
      float2 ss = scsh1[cg * 16 + c_l];
      v = fmaxf(0.f, y1[((size_t)(b * CM_) + cg * 16 + c_l) * 4096 + row * 64 + col] * ss.x + ss.y);
    }
    lkb[c_l][gri][j] = (unsigned short)f2bf(v);
  }
  __syncthreads();

  float acc[4][4];
#pragma unroll
  for (int cc = 0; cc < 4; cc++)
#pragma unroll
    for (int h_i = 0; h_i < 4; h_i++) acc[cc][h_i] = 0.f;

  const float* ab = att_t + (size_t)b * 81 * 4096 + h0 * 64 + lane;

#pragma unroll
  for (int gri = 0; gri < 12; ++gri) {
    float win[4][9];
#pragma unroll
    for (int cc = 0; cc < 4; ++cc)
#pragma unroll
      for (int dw = 0; dw < 9; ++dw)
        win[cc][dw] = bf2f(lkb[wv * 4 + cc][gri][lane + dw]);
#pragma unroll
    for (int h_i = 0; h_i < 4; ++h_i) {
      int r = gri - h_i;
      if (r < 0 || r > 8) continue;
      const float* ap = ab + (size_t)(r * 9) * 4096 + h_i * 64;
      float a[9];
#pragma unroll
      for (int dw = 0; dw < 9; ++dw) a[dw] = ap[(size_t)dw * 4096];
#pragma unroll
      for (int cc = 0; cc < 4; ++cc)
#pragma unroll
        for (int dw = 0; dw < 9; ++dw)
          acc[cc][h_i] = fmaf(a[dw], win[cc][dw], acc[cc][h_i]);
    }
  }

#pragma unroll
  for (int cc = 0; cc < 4; ++cc) {
    int c = cg * 16 + wv * 4 + cc;
    float2 ss4 = scsh4[c];
    int icb = c & 31;
    int uu = (icb >> 3) ^ ((lane >> 1) & 3);
#pragma unroll
    for (int h_i = 0; h_i < 4; ++h_i) {
      int h = h0 + h_i;
      size_t gi = ((size_t)(b * CM_) + c) * 4096 + h * 64 + lane;
      float lnk = fmaxf(0.f, y4[gi] * ss4.x + ss4.y);
      float dv = acc[cc][h_i] - lnk;
      xt5[((((size_t)b * 4 + (c >> 5)) * 64 + h) * 64 + lane) * 32 + uu * 8 + (icb & 7)] =
          f2bf(dv);
    }
  }
}

// ---- fc1 + fc2 -------------------------------------------------------------
__global__ void fc_kernel(const float* __restrict__ pooled, const float* __restrict__ fc1w,
                          const float* __restrict__ fc1b, const float* __restrict__ fc2w,
                          const float* __restrict__ fc2b, float* __restrict__ out) {
  int lane = threadIdx.x;
  float p[B_][10];
#pragma unroll
  for (int b = 0; b < B_; b++)
#pragma unroll
    for (int j = 0; j < 10; j++) p[b][j] = 0.f;
  for (int c = lane; c < CM_; c += 64) {
#pragma unroll
    for (int b = 0; b < B_; b++) {
      float pv = pooled[b * CM_ + c];
#pragma unroll
      for (int j = 0; j < 10; j++) p[b][j] = fmaf(pv, fc1w[j * CM_ + c], p[b][j]);
    }
  }
  for (int off = 32; off > 0; off >>= 1)
#pragma unroll
    for (int b = 0; b < B_; b++)
#pragma unroll
      for (int j = 0; j < 10; j++) p[b][j] += __shfl_down(p[b][j], off);
  if (lane == 0) {
    for (int b = 0; b < B_; b++) {
      float o = fc2b[0];
      for (int j = 0; j < 10; j++) o += fc2w[j] * (p[b][j] + fc1b[j]);
      out[b] = o;
    }
  }
}

extern "C" void kernel_launch(void* const* d_in, const int* in_sizes, int n_in,
                              void* d_out, int out_size, void* d_ws, size_t ws_size,
                              hipStream_t stream) {
  const float* low_key    = (const float*)d_in[0];
  const float* low_nonkey = (const float*)d_in[1];
  const float* atten      = (const float*)d_in[2];
  const float* w1  = (const float*)d_in[3];
  const float* g1  = (const float*)d_in[4];
  const float* b1  = (const float*)d_in[5];
  const float* w4  = (const float*)d_in[6];
  const float* g4  = (const float*)d_in[7];
  const float* b4  = (const float*)d_in[8];
  const float* w5  = (const float*)d_in[9];
  const float* g5  = (const float*)d_in[10];
  const float* b5  = (const float*)d_in[11];
  const float* fc1w = (const float*)d_in[12];
  const float* fc1b = (const float*)d_in[13];
  const float* fc2w = (const float*)d_in[14];
  const float* fc2b = (const float*)d_in[15];

  char* w8 = (char*)d_ws;
  short* wf1   = (short*)w8;                       // 2,359,296 B
  short* wf4   = (short*)(w8 + 2359296);           // 2,359,296 B
  short* wf5   = (short*)(w8 + 4718592);           //   294,912 B (pad to 589,824)
  float* att_t = (float*)(w8 + 5308416);           // 5,308,416 B
  short* xt    = (short*)(w8 + 10616832);          // 33,554,432 B (xt5 aliases base)
  float* y1    = (float*)(w8 + 44171264);          // 8,388,608 B (zeroed; conv1 acc; y5a)
  float* y4    = (float*)(w8 + 52559872);          // 8,388,608 B (zeroed; conv4 acc; y5b)
  float2* scsh1 = (float2*)(w8 + 60948480);
  float2* scsh4 = scsh1 + CM_;
  float2* scsh5 = scsh4 + CM_;
  float* pooled = (float*)(scsh5 + CM_);
  short* xt5 = xt;  // conv5 input, written by localw after xt is dead
  float* out = (float*)d_out;

  // 1. fused prep: xt(low_key), wf1/wf4/wf5 fragment-major, att_t, zero y1+y4
  prep1_kernel<<<7488, 256, 0, stream>>>(low_key, w1, w4, w5, atten,
                                         xt, wf1, wf4, wf5, att_t, y1);
  // 2. conv1: uneven K-split x6 -> 768 blocks = exactly 3 blocks/CU, atomic y1
  convm_kernel<true, 0, true><<<dim3(128, 6), 256, 0, stream>>>(xt, wf1, y1, y1, 32);
  // 3. xprep for low_nonkey (reuses xt)
  xprep_kernel<32><<<dim3(512, 4), 256, 0, stream>>>(low_nonkey, xt);
  // 4. conv4
  convm_kernel<true, 0, true><<<dim3(128, 6), 256, 0, stream>>>(xt, wf4, y4, y4, 32);
  // 5. BN stats for conv1 & conv4 in one launch
  bnstats2_kernel<<<dim3(128, 2), 256, 0, stream>>>(y1, g1, b1, scsh1, y4, g4, b4, scsh4);
  // 6. local weighting + subtract -> xt5 (bf16 conv5 layout)
  localw_kernel<<<dim3(64, 8), 256, 0, stream>>>(y1, scsh1, y4, scsh4, att_t, xt5);
  // 7. conv5: K-split x2, non-atomic partials into now-dead y1/y4 regions
  convm_kernel<false, 2, false><<<dim3(128, 2), 256, 0, stream>>>(xt5, wf5, y1, y4, 4);
  // 8+9. BN stats over y5 = y1+y4 partials, fused with pool
  bnpool_kernel<<<128, 256, 0, stream>>>(y1, y4, g5, b5, pooled);
  // 10. fc
  fc_kernel<<<1, 64, 0, stream>>>(pooled, fc1w, fc1b, fc2w, fc2b, out);
}

// Round 7
// 372.344 us; speedup vs baseline: 1.1989x; 1.0794x over previous
//
#include <hip/hip_runtime.h>
#include <hip/hip_bf16.h>

// KeySelect2 round 12: revert-and-consolidate. Six convm variants establish
// the conv is at m97-structural parity (~33% of MFMA peak) and invariant to
// sync structure AND occupancy (r6: 3 clean blocks/CU, same per-kb throughput).
// Best measured convm = round-1 8-phase ring (55.6us) -- restored VERBATIM.
// New: xprep(low_nonkey) folded into prep1 writing a separate xt4 buffer,
// GATED on ws_size >= 94.5MB at the host (fallback = exact r1 sequence), which
// removes the serial xprep launch between conv1 and conv4. bnpool fusion kept.

#define B_ 4
#define CM_ 128

typedef __attribute__((ext_vector_type(8))) short short8;
typedef __attribute__((ext_vector_type(4))) float floatx4;
typedef __attribute__((address_space(3))) unsigned lds_as;
typedef __attribute__((address_space(1))) const unsigned glb_as;

__device__ inline short f2bf(float f) {
  union { float f; unsigned u; } v; v.f = f;
  unsigned r = v.u + 0x7fff + ((v.u >> 16) & 1);  // RNE
  return (short)(r >> 16);
}
__device__ inline float bf2f(unsigned short u) {
  union { unsigned u; float f; } v; v.u = ((unsigned)u) << 16;
  return v.f;
}

template <int N> __device__ __forceinline__ void waitv() {
  static_assert(N == 0 || N == 2 || N == 4 || N == 6 || N == 10, "bad vmcnt");
  if constexpr (N == 0) asm volatile("s_waitcnt vmcnt(0)" ::: "memory");
  else if constexpr (N == 2) asm volatile("s_waitcnt vmcnt(2)" ::: "memory");
  else if constexpr (N == 4) asm volatile("s_waitcnt vmcnt(4)" ::: "memory");
  else if constexpr (N == 6) asm volatile("s_waitcnt vmcnt(6)" ::: "memory");
  else asm volatile("s_waitcnt vmcnt(10)" ::: "memory");
}

// ---- x prepack: NCHW fp32 -> [b][kb][row][col][unit^sw][8] bf16 ------------
template <int KB>
__global__ void xprep_kernel(const float* __restrict__ x, short* __restrict__ xt) {
  int kb = blockIdx.x >> 4, rg = blockIdx.x & 15;
  int b = blockIdx.y;
  int row = rg * 4 + (threadIdx.x >> 6);
  int col = threadIdx.x & 63;
  const float* xs = x + (((size_t)b * (KB * 32) + kb * 32) * 64 + row) * 64 + col;
  short* xd = xt + ((((size_t)b * KB + kb) * 64 + row) * 64 + col) * 32;
  int sw = (col >> 1) & 3;
#pragma unroll
  for (int u = 0; u < 4; u++) {
    short8 pk;
#pragma unroll
    for (int j = 0; j < 8; j++) pk[j] = f2bf(xs[(size_t)(u * 8 + j) * 4096]);
    *(short8*)(xd + (u ^ sw) * 8) = pk;
  }
}

// ---- fused prep: xprep(low_key [+low_nonkey if xt4]), wfrag 1/4/5,
//      att transpose, zero y1+y4 ----------------------------------------------
__global__ void prep1_kernel(const float* __restrict__ x1, const float* __restrict__ x4,
                             const float* __restrict__ w1, const float* __restrict__ w4,
                             const float* __restrict__ w5, const float* __restrict__ atten,
                             short* __restrict__ xt, short* __restrict__ xt4,
                             short* __restrict__ wf1,
                             short* __restrict__ wf4, short* __restrict__ wf5,
                             float* __restrict__ att_t, float* __restrict__ yz) {
  __shared__ float tile[5184];
  int bx = blockIdx.x, tid = threadIdx.x;
  if (bx < 2048) {  // xprep for low_key
    int b = bx & 3, t = bx >> 2;
    int kb = t >> 4, rg = t & 15;
    int row = rg * 4 + (tid >> 6), col = tid & 63;
    const float* xs = x1 + (((size_t)b * 1024 + kb * 32) * 64 + row) * 64 + col;
    short* xd = xt + ((((size_t)b * 32 + kb) * 64 + row) * 64 + col) * 32;
    int sw = (col >> 1) & 3;
#pragma unroll
    for (int u = 0; u < 4; u++) {
      short8 pk;
#pragma unroll
      for (int j = 0; j < 8; j++) pk[j] = f2bf(xs[(size_t)(u * 8 + j) * 4096]);
      *(short8*)(xd + (u ^ sw) * 8) = pk;
    }
    return;
  }
  bx -= 2048;
  if (bx < 1024) {  // wf1 / wf4 (cin=1024)
    const float* w = bx < 512 ? w1 : w4;
    short* wf = bx < 512 ? wf1 : wf4;
    int idx = (bx & 511) * 256 + tid;
    int oc = idx >> 10, ic = idx & 1023;
    int kb = ic >> 5, icb = ic & 31, quad = icb >> 3, j = icb & 7;
    int m = oc >> 4, n16 = oc & 15, lane = quad * 16 + n16;
    const float* wp = w + ((size_t)oc * 1024 + ic) * 9;
    short* base = wf + (size_t)kb * 36864 + lane * 8 + j;
#pragma unroll
    for (int r = 0; r < 3; r++)
#pragma unroll
      for (int s = 0; s < 3; s++)
        base[(size_t)r * 12288 + (s * 8 + m) * 512] = f2bf(wp[r * 3 + s]);
    return;
  }
  bx -= 1024;
  if (bx < 64) {  // wf5 (cin=128)
    int idx = bx * 256 + tid;
    int oc = idx >> 7, ic = idx & 127;
    int kb = ic >> 5, icb = ic & 31, quad = icb >> 3, j = icb & 7;
    int m = oc >> 4, n16 = oc & 15, lane = quad * 16 + n16;
    const float* wp = w5 + ((size_t)oc * 128 + ic) * 9;
    short* base = wf5 + (size_t)kb * 36864 + lane * 8 + j;
#pragma unroll
    for (int r = 0; r < 3; r++)
#pragma unroll
      for (int s = 0; s < 3; s++)
        base[(size_t)r * 12288 + (s * 8 + m) * 512] = f2bf(wp[r * 3 + s]);
    return;
  }
  bx -= 64;
  if (bx < 256) {  // atten [b,pix,81] -> att_t [b,81,pix]
    int b = bx >> 6;
    int p0 = (bx & 63) * 64;
    const float* src = atten + ((size_t)b * 4096 + p0) * 81;
    for (int e = tid; e < 5184; e += 256) tile[e] = src[e];
    __syncthreads();
    for (int f = tid; f < 5184; f += 256) {
      int k = f >> 6, w_ = f & 63;
      att_t[((size_t)b * 81 + k) * 4096 + p0 + w_] = tile[w_ * 81 + k];
    }
    return;
  }
  bx -= 256;
  if (bx < 4096) {  // zero y1+y4 (16,777,216 B)
    ((float4*)yz)[(size_t)bx * 256 + tid] = make_float4(0.f, 0.f, 0.f, 0.f);
    return;
  }
  bx -= 4096;
  {  // xprep for low_nonkey -> xt4 (only launched when ws fits xt4)
    int b = bx & 3, t = bx >> 2;
    int kb = t >> 4, rg = t & 15;
    int row = rg * 4 + (tid >> 6), col = tid & 63;
    const float* xs = x4 + (((size_t)b * 1024 + kb * 32) * 64 + row) * 64 + col;
    short* xd = xt4 + ((((size_t)b * 32 + kb) * 64 + row) * 64 + col) * 32;
    int sw = (col >> 1) & 3;
#pragma unroll
    for (int u = 0; u < 4; u++) {
      short8 pk;
#pragma unroll
      for (int j = 0; j < 8; j++) pk[j] = f2bf(xs[(size_t)(u * 8 + j) * 4096]);
      *(short8*)(xd + (u ^ sw) * 8) = pk;
    }
  }
}

// ---- MFMA conv, per-tap phase pipeline (round-1 kernel, verified 55.6us) ---
// grid (128, KSPLIT); block 256 (4 waves). Block tile 128 oc x 128 pix (2 rows).
// LDS (80 KB): w ring 6 tap-slots x 4096 shorts ([m8][lane64][8]);
//              x double buffer 2 x (4 slots x 2048 shorts).
template <int KQ, bool ATOMIC>
__global__ __launch_bounds__(256, 2)
void convm_kernel(const short* __restrict__ xt, const short* __restrict__ wf,
                  float* __restrict__ ya, float* __restrict__ yb, int KBtot) {
  __shared__ __attribute__((aligned(16))) short smem[40960];  // 80 KB
  int tid = threadIdx.x, lane = tid & 63, wv = tid >> 6;
  int n16 = lane & 15, quad = lane >> 4;
  int pg = blockIdx.x;
  int b = pg >> 5, h0 = (pg & 31) * 2;
  int kb0 = blockIdx.y * KQ;
  int mh = wv & 1, nh = wv >> 1;
  float* yo = ATOMIC ? ya : (blockIdx.y ? yb : ya);
  short* sx0 = smem + 24576;

  // pre-zero boundary x slots in BOTH buffers (never DMA'd)
  if (h0 == 0)
    for (int i = tid; i < 1024; i += 256) {
      ((int*)sx0)[i] = 0;
      ((int*)(sx0 + 8192))[i] = 0;
    }
  if (h0 == 62)
    for (int i = tid; i < 1024; i += 256) {
      ((int*)(sx0 + 3 * 2048))[i] = 0;
      ((int*)(sx0 + 8192 + 3 * 2048))[i] = 0;
    }

  int row = h0 - 1 + wv;  // wave wv stages x slot wv
  int xw = __builtin_amdgcn_readfirstlane((row >= 0 && row < 64) ? 1 : 0);
  const short* wfb = wf + (size_t)kb0 * 36864;

  // loop-invariant B-read offsets (shorts) + boundary-zero masks
  int boff[3][4];
#pragma unroll
  for (int sp = 0; sp < 3; sp++)
#pragma unroll
    for (int n = 0; n < 4; n++) {
      int c = n * 16 + n16 + sp - 1;
      int cc = c < 0 ? 0 : (c > 63 ? 63 : c);
      boff[sp][n] = cc * 32 + (quad ^ ((cc >> 1) & 3)) * 8;
    }
  bool bz00 = (n16 == 0), bz32 = (n16 == 15);

  floatx4 acc[4][4];
#pragma unroll
  for (int i = 0; i < 4; i++)
#pragma unroll
    for (int n = 0; n < 4; n++) acc[i][n] = (floatx4){0.f, 0.f, 0.f, 0.f};

  // ---- prologue: x(kb0) -> xbuf0; w phases 0..3 -> ring slots 0..3 ----
  if (xw) {
    const short* xs = xt + ((((size_t)b * KBtot + kb0) * 64 + row) * 64) * 32 + lane * 8;
    short* xd = sx0 + wv * 2048 + lane * 8;
#pragma unroll
    for (int t = 0; t < 4; t++)
      __builtin_amdgcn_global_load_lds((glb_as*)(xs + t * 512), (lds_as*)(xd + t * 512),
                                       16, 0, 0);
  }
#pragma unroll
  for (int p = 0; p < 4; p++) {
    const short* ws = wfb + (size_t)p * 4096 + wv * 1024 + lane * 8;
    short* wd = smem + p * 4096 + wv * 1024 + lane * 8;
    __builtin_amdgcn_global_load_lds((glb_as*)ws, (lds_as*)wd, 16, 0, 0);
    __builtin_amdgcn_global_load_lds((glb_as*)(ws + 512), (lds_as*)(wd + 512), 16, 0, 0);
  }
  asm volatile("s_waitcnt lgkmcnt(0)" ::: "memory");  // boundary-slot zeroes visible
  waitv<6>();  // x + w slot0 landed (queue: x?,w0,w1,w2,w3 -> leave 6)
  __builtin_amdgcn_s_barrier();

#define PHASE(E, DO_W, DO_X, VX, VN, DO_TAIL)                                        \
  {                                                                                  \
    constexpr int rr_ = (E) / 3, sp_ = (E) % 3;                                      \
    int ts_ = qp + (E); ts_ = ts_ >= 6 ? ts_ - 6 : ts_;                              \
    const short* swt_ = smem + ts_ * 4096;                                           \
    short8 a_[4];                                                                    \
    _Pragma("unroll")                                                                \
    for (int i = 0; i < 4; i++)                                                      \
      a_[i] = *(const short8*)(swt_ + ((mh * 4 + i) * 64 + lane) * 8);               \
    const short* sxr_ = sxread + (nh + rr_) * 2048;                                  \
    short8 bf_[4];                                                                   \
    _Pragma("unroll")                                                                \
    for (int n = 0; n < 4; n++) {                                                    \
      short8 bv = *(const short8*)(sxr_ + boff[sp_][n]);                             \
      if ((n == 0 && sp_ == 0) || (n == 3 && sp_ == 2)) {                            \
        short8 zz = {0, 0, 0, 0, 0, 0, 0, 0};                                        \
        bool bz = (sp_ == 0) ? bz00 : bz32;                                          \
        bv = bz ? zz : bv;                                                           \
      }                                                                              \
      bf_[n] = bv;                                                                   \
    }                                                                                \
    if (DO_W) {                                                                      \
      int t2_ = qp + (E) + 4;                                                        \
      t2_ = t2_ >= 12 ? t2_ - 12 : (t2_ >= 6 ? t2_ - 6 : t2_);                       \
      const short* ws_ = wfb + (size_t)(9 * q + (E) + 4) * 4096 + wv * 1024 + lane * 8; \
      short* wd_ = smem + t2_ * 4096 + wv * 1024 + lane * 8;                         \
      __builtin_amdgcn_global_load_lds((glb_as*)ws_, (lds_as*)wd_, 16, 0, 0);        \
      __builtin_amdgcn_global_load_lds((glb_as*)(ws_ + 512), (lds_as*)(wd_ + 512),   \
                                       16, 0, 0);                                    \
    }                                                                                \
    if (DO_X) {                                                                      \
      if (xw) {                                                                      \
        const short* xs_ = xt +                                                      \
            ((((size_t)b * KBtot + kb0 + q + 1) * 64 + row) * 64) * 32 + lane * 8;   \
        short* xd_ = sxwr + wv * 2048 + lane * 8;                                    \
        _Pragma("unroll")                                                            \
        for (int t = 0; t < 4; t++)                                                  \
          __builtin_amdgcn_global_load_lds((glb_as*)(xs_ + t * 512),                 \
                                           (lds_as*)(xd_ + t * 512), 16, 0, 0);      \
      }                                                                              \
    }                                                                                \
    __builtin_amdgcn_s_barrier();                                                    \
    __builtin_amdgcn_s_setprio(1);                                                   \
    _Pragma("unroll")                                                                \
    for (int n = 0; n < 4; n++)                                                      \
      _Pragma("unroll")                                                              \
      for (int i = 0; i < 4; i++)                                                    \
        acc[i][n] =                                                                  \
            __builtin_amdgcn_mfma_f32_16x16x32_bf16(a_[i], bf_[n], acc[i][n], 0, 0, 0); \
    __builtin_amdgcn_s_setprio(0);                                                   \
    if (DO_TAIL) {                                                                   \
      if ((VX) != (VN) && xw) { waitv<(VX)>(); } else { waitv<(VN)>(); }             \
      __builtin_amdgcn_s_barrier();                                                  \
    }                                                                                \
  }

  for (int q = 0; q < KQ - 1; ++q) {  // main kbs (issue w every phase, x at e=1)
    int qp = (q & 1) * 3;
    const short* sxread = sx0 + (q & 1) * 8192;
    short* sxwr = sx0 + ((q + 1) & 1) * 8192;
    PHASE(0, true, false, 6, 6, true)
    PHASE(1, true, true, 10, 6, true)
    PHASE(2, true, false, 10, 6, true)
    PHASE(3, true, false, 10, 6, true)
    PHASE(4, true, false, 10, 6, true)
    PHASE(5, true, false, 6, 6, true)
    PHASE(6, true, false, 6, 6, true)
    PHASE(7, true, false, 6, 6, true)
    PHASE(8, true, false, 6, 6, true)
  }
  {  // epilogue kb: issues stop after e=4; tail literals 6,6,6,6,6,4,2,0
    const int q = KQ - 1;
    int qp = (q & 1) * 3;
    const short* sxread = sx0 + (q & 1) * 8192;
    short* sxwr = nullptr; (void)sxwr;
    PHASE(0, true, false, 6, 6, true)
    PHASE(1, true, false, 6, 6, true)
    PHASE(2, true, false, 6, 6, true)
    PHASE(3, true, false, 6, 6, true)
    PHASE(4, true, false, 6, 6, true)
    PHASE(5, false, false, 4, 4, true)
    PHASE(6, false, false, 2, 2, true)
    PHASE(7, false, false, 0, 0, true)
    PHASE(8, false, false, 0, 0, false)
  }
#undef PHASE

  int orow = h0 + nh;
#pragma unroll
  for (int i = 0; i < 4; i++)
#pragma unroll
    for (int n = 0; n < 4; n++)
#pragma unroll
      for (int rg = 0; rg < 4; rg++) {
        int oc = mh * 64 + i * 16 + quad * 4 + rg;  // D: row=quad*4+reg, col=n16
        size_t gi = (((size_t)b * CM_ + oc) * 64 + orow) * 64 + n * 16 + n16;
        if (ATOMIC)
          atomicAdd(&yo[gi], acc[i][n][rg]);
        else
          yo[gi] = acc[i][n][rg];
      }
}

// ---- BN stats (pair: by=0 -> set1, by=1 -> set4) ---------------------------
__global__ void bnstats2_kernel(const float* __restrict__ y1, const float* __restrict__ g1,
                                const float* __restrict__ b1, float2* __restrict__ s1,
                                const float* __restrict__ y4, const float* __restrict__ g4,
                                const float* __restrict__ b4, float2* __restrict__ s4) {
  const float* y = blockIdx.y ? y4 : y1;
  const float* g = blockIdx.y ? g4 : g1;
  const float* bt = blockIdx.y ? b4 : b1;
  float2* scsh = blockIdx.y ? s4 : s1;
  int c = blockIdx.x;
  int tid = threadIdx.x;
  float s = 0.f, s2 = 0.f;
  for (int b = 0; b < B_; b++) {
    const float4* p = (const float4*)(y + ((size_t)(b * CM_) + c) * 4096);
    for (int i = tid; i < 1024; i += 256) {
      float4 v = p[i];
      s += v.x + v.y + v.z + v.w;
      s2 += v.x * v.x + v.y * v.y + v.z * v.z + v.w * v.w;
    }
  }
  for (int off = 32; off > 0; off >>= 1) {
    s += __shfl_down(s, off);
    s2 += __shfl_down(s2, off);
  }
  __shared__ float rs[4], rq[4];
  if ((tid & 63) == 0) { rs[tid >> 6] = s; rq[tid >> 6] = s2; }
  __syncthreads();
  if (tid == 0) {
    float S = rs[0] + rs[1] + rs[2] + rs[3];
    float Q = rq[0] + rq[1] + rq[2] + rq[3];
    float mean = S * (1.f / 16384.f);
    float var = Q * (1.f / 16384.f) - mean * mean;
    float sc = g[c] * rsqrtf(var + 1e-5f);
    scsh[c] = make_float2(sc, bt[c] - mean * sc);
  }
}

// ---- BN stats over y5 = ya+yb, then fused pool (pass 2 is L2-hot) ----------
__global__ void bnpool_kernel(const float* __restrict__ ya, const float* __restrict__ yb,
                              const float* __restrict__ g, const float* __restrict__ bt,
                              float* __restrict__ pooled) {
  int c = blockIdx.x;
  int tid = threadIdx.x;
  float s = 0.f, s2 = 0.f;
  for (int b = 0; b < B_; b++) {
    const float4* p = (const float4*)(ya + ((size_t)(b * CM_) + c) * 4096);
    const float4* q = (const float4*)(yb + ((size_t)(b * CM_) + c) * 4096);
    for (int i = tid; i < 1024; i += 256) {
      float4 v = p[i], w = q[i];
      float a0 = v.x + w.x, a1 = v.y + w.y, a2 = v.z + w.z, a3 = v.w + w.w;
      s += a0 + a1 + a2 + a3;
      s2 += a0 * a0 + a1 * a1 + a2 * a2 + a3 * a3;
    }
  }
  for (int off = 32; off > 0; off >>= 1) {
    s += __shfl_down(s, off);
    s2 += __shfl_down(s2, off);
  }
  __shared__ float rs[4], rq[4];
  __shared__ float2 ss_sh;
  if ((tid & 63) == 0) { rs[tid >> 6] = s; rq[tid >> 6] = s2; }
  __syncthreads();
  if (tid == 0) {
    float S = rs[0] + rs[1] + rs[2] + rs[3];
    float Q = rq[0] + rq[1] + rq[2] + rq[3];
    float mean = S * (1.f / 16384.f);
    float var = Q * (1.f / 16384.f) - mean * mean;
    float sc = g[c] * rsqrtf(var + 1e-5f);
    ss_sh = make_float2(sc, bt[c] - mean * sc);
  }
  __syncthreads();
  float2 ss = ss_sh;
  float pb[B_];
#pragma unroll
  for (int b = 0; b < B_; b++) pb[b] = 0.f;
  for (int b = 0; b < B_; b++) {
    const float4* p = (const float4*)(ya + ((size_t)(b * CM_) + c) * 4096);
    const float4* q = (const float4*)(yb + ((size_t)(b * CM_) + c) * 4096);
    for (int i = tid; i < 1024; i += 256) {
      float4 v = p[i], w = q[i];
      pb[b] += fmaxf(0.f, (v.x + w.x) * ss.x + ss.y) + fmaxf(0.f, (v.y + w.y) * ss.x + ss.y) +
               fmaxf(0.f, (v.z + w.z) * ss.x + ss.y) + fmaxf(0.f, (v.w + w.w) * ss.x + ss.y);
    }
  }
  for (int off = 32; off > 0; off >>= 1)
#pragma unroll
    for (int b = 0; b < B_; b++) pb[b] += __shfl_down(pb[b], off);
  __shared__ float pbs[4][B_];
  if ((tid & 63) == 0)
#pragma unroll
    for (int b = 0; b < B_; b++) pbs[tid >> 6][b] = pb[b];
  __syncthreads();
  if (tid < B_)
    pooled[tid * CM_ + c] =
        (pbs[0][tid] + pbs[1][tid] + pbs[2][tid] + pbs[3][tid]) * (1.f / 4096.f);
}

// ---- local weighting + subtract -> xt5 (bf16, conv5 layout) ----------------
__global__ __launch_bounds__(256, 2)
void localw_kernel(const float* __restrict__ y1, const float2* __restrict__ scsh1,
                   const float* __restrict__ y4, const float2* __restrict__ scsh4,
                   const float* __restrict__ att_t, short* __restrict__ xt5) {
  __shared__ unsigned short lkb[16][12][72];
  int bx = blockIdx.x;
  int b = bx >> 4, h0 = (bx & 15) * 4;
  int cg = blockIdx.y;
  int tid = threadIdx.x;
  int lane = tid & 63;
  int wv = tid >> 6;

  for (int e = tid; e < 16 * 12 * 72; e += 256) {
    int c_l = e / (12 * 72);
    int rem = e % (12 * 72);
    int gri = rem / 72, j = rem % 72;
    int row = h0 - 4 + gri, col = j - 4;
    float v = 0.f;
    if (row >= 0 && row < 64 && col >= 0 && col < 64) {
      float2 ss = scsh1[cg * 16 + c_l];
      v = fmaxf(0.f, y1[((size_t)(b * CM_) + cg * 16 + c_l) * 4096 + row * 64 + col] * ss.x + ss.y);
    }
    lkb[c_l][gri][j] = (unsigned short)f2bf(v);
  }
  __syncthreads();

  float acc[4][4];
#pragma unroll
  for (int cc = 0; cc < 4; cc++)
#pragma unroll
    for (int h_i = 0; h_i < 4; h_i++) acc[cc][h_i] = 0.f;

  const float* ab = att_t + (size_t)b * 81 * 4096 + h0 * 64 + lane;

#pragma unroll
  for (int gri = 0; gri < 12; ++gri) {
    float win[4][9];
#pragma unroll
    for (int cc = 0; cc < 4; ++cc)
#pragma unroll
      for (int dw = 0; dw < 9; ++dw)
        win[cc][dw] = bf2f(lkb[wv * 4 + cc][gri][lane + dw]);
#pragma unroll
    for (int h_i = 0; h_i < 4; ++h_i) {
      int r = gri - h_i;
      if (r < 0 || r > 8) continue;
      const float* ap = ab + (size_t)(r * 9) * 4096 + h_i * 64;
      float a[9];
#pragma unroll
      for (int dw = 0; dw < 9; ++dw) a[dw] = ap[(size_t)dw * 4096];
#pragma unroll
      for (int cc = 0; cc < 4; ++cc)
#pragma unroll
        for (int dw = 0; dw < 9; ++dw)
          acc[cc][h_i] = fmaf(a[dw], win[cc][dw], acc[cc][h_i]);
    }
  }

#pragma unroll
  for (int cc = 0; cc < 4; ++cc) {
    int c = cg * 16 + wv * 4 + cc;
    float2 ss4 = scsh4[c];
    int icb = c & 31;
    int uu = (icb >> 3) ^ ((lane >> 1) & 3);
#pragma unroll
    for (int h_i = 0; h_i < 4; ++h_i) {
      int h = h0 + h_i;
      size_t gi = ((size_t)(b * CM_) + c) * 4096 + h * 64 + lane;
      float lnk = fmaxf(0.f, y4[gi] * ss4.x + ss4.y);
      float dv = acc[cc][h_i] - lnk;
      xt5[((((size_t)b * 4 + (c >> 5)) * 64 + h) * 64 + lane) * 32 + uu * 8 + (icb & 7)] =
          f2bf(dv);
    }
  }
}

// ---- fc1 + fc2 -------------------------------------------------------------
__global__ void fc_kernel(const float* __restrict__ pooled, const float* __restrict__ fc1w,
                          const float* __restrict__ fc1b, const float* __restrict__ fc2w,
                          const float* __restrict__ fc2b, float* __restrict__ out) {
  int lane = threadIdx.x;
  float p[B_][10];
#pragma unroll
  for (int b = 0; b < B_; b++)
#pragma unroll
    for (int j = 0; j < 10; j++) p[b][j] = 0.f;
  for (int c = lane; c < CM_; c += 64) {
#pragma unroll
    for (int b = 0; b < B_; b++) {
      float pv = pooled[b * CM_ + c];
#pragma unroll
      for (int j = 0; j < 10; j++) p[b][j] = fmaf(pv, fc1w[j * CM_ + c], p[b][j]);
    }
  }
  for (int off = 32; off > 0; off >>= 1)
#pragma unroll
    for (int b = 0; b < B_; b++)
#pragma unroll
      for (int j = 0; j < 10; j++) p[b][j] += __shfl_down(p[b][j], off);
  if (lane == 0) {
    for (int b = 0; b < B_; b++) {
      float o = fc2b[0];
      for (int j = 0; j < 10; j++) o += fc2w[j] * (p[b][j] + fc1b[j]);
      out[b] = o;
    }
  }
}

extern "C" void kernel_launch(void* const* d_in, const int* in_sizes, int n_in,
                              void* d_out, int out_size, void* d_ws, size_t ws_size,
                              hipStream_t stream) {
  const float* low_key    = (const float*)d_in[0];
  const float* low_nonkey = (const float*)d_in[1];
  const float* atten      = (const float*)d_in[2];
  const float* w1  = (const float*)d_in[3];
  const float* g1  = (const float*)d_in[4];
  const float* b1  = (const float*)d_in[5];
  const float* w4  = (const float*)d_in[6];
  const float* g4  = (const float*)d_in[7];
  const float* b4  = (const float*)d_in[8];
  const float* w5  = (const float*)d_in[9];
  const float* g5  = (const float*)d_in[10];
  const float* b5  = (const float*)d_in[11];
  const float* fc1w = (const float*)d_in[12];
  const float* fc1b = (const float*)d_in[13];
  const float* fc2w = (const float*)d_in[14];
  const float* fc2b = (const float*)d_in[15];

  char* w8 = (char*)d_ws;
  short* wf1   = (short*)w8;                       // 2,359,296 B
  short* wf4   = (short*)(w8 + 2359296);           // 2,359,296 B
  short* wf5   = (short*)(w8 + 4718592);           //   294,912 B (pad to 589,824)
  float* att_t = (float*)(w8 + 5308416);           // 5,308,416 B
  short* xt    = (short*)(w8 + 10616832);          // 33,554,432 B (xt5 aliases base)
  float* y1    = (float*)(w8 + 44171264);          // 8,388,608 B (zeroed; conv1 acc; y5a)
  float* y4    = (float*)(w8 + 52559872);          // 8,388,608 B (zeroed; conv4 acc; y5b)
  float2* scsh1 = (float2*)(w8 + 60948480);
  float2* scsh4 = scsh1 + CM_;
  float2* scsh5 = scsh4 + CM_;
  float* pooled = (float*)(scsh5 + CM_);
  short* xt5 = xt;  // conv5 input, written by localw after xt is dead
  float* out = (float*)d_out;

  // optional second x buffer for low_nonkey (removes serial xprep launch);
  // gated on workspace size -- fallback path is the verified r1 sequence.
  const size_t XT4_OFF = 60956672;                 // 1 KiB-aligned, past scsh/pooled
  bool big = ws_size >= (size_t)(XT4_OFF + 33554432);
  short* xt4 = big ? (short*)(w8 + XT4_OFF) : nullptr;

  // 1. fused prep: xt(low_key) [+ xt4(low_nonkey) if big], wf1/wf4/wf5,
  //    att_t, zero y1+y4
  prep1_kernel<<<big ? 9536 : 7488, 256, 0, stream>>>(
      low_key, low_nonkey, w1, w4, w5, atten, xt, xt4, wf1, wf4, wf5, att_t, y1);
  // 2. conv1: K-split x4, atomic accumulate into zeroed y1
  convm_kernel<8, true><<<dim3(128, 4), 256, 0, stream>>>(xt, wf1, y1, y1, 32);
  // 3. xprep for low_nonkey (only if xt4 didn't fit; reuses xt)
  if (!big) xprep_kernel<32><<<dim3(512, 4), 256, 0, stream>>>(low_nonkey, xt);
  // 4. conv4
  convm_kernel<8, true><<<dim3(128, 4), 256, 0, stream>>>(big ? xt4 : xt, wf4, y4, y4, 32);
  // 5. BN stats for conv1 & conv4 in one launch
  bnstats2_kernel<<<dim3(128, 2), 256, 0, stream>>>(y1, g1, b1, scsh1, y4, g4, b4, scsh4);
  // 6. local weighting + subtract -> xt5 (bf16 conv5 layout)
  localw_kernel<<<dim3(64, 8), 256, 0, stream>>>(y1, scsh1, y4, scsh4, att_t, xt5);
  // 7. conv5: K-split x2, non-atomic partials into now-dead y1/y4 regions
  convm_kernel<2, false><<<dim3(128, 2), 256, 0, stream>>>(xt5, wf5, y1, y4, 4);
  // 8+9. BN stats over y5 = y1+y4 partials, fused with pool
  bnpool_kernel<<<128, 256, 0, stream>>>(y1, y4, g5, b5, pooled);
  // 10. fc
  fc_kernel<<<1, 64, 0, stream>>>(pooled, fc1w, fc1b, fc2w, fc2b, out);
}